// Round 10
// baseline (243.565 us; speedup 1.0000x reference)
//
#include <hip/hip_runtime.h>
#include <cstdint>

#define NNODES 100000
#define NEDGES 1200000
#define INF 64
#define OUTF 32
#define SCAN_B 256
#define NBUCK ((NNODES + SCAN_B - 1) / SCAN_B)   // 391; bucket b = dst >> 8
#define PCAP 4608                                 // slots/bucket (R3/R4-verified)
#define BIN_EPT 16
#define BIN_THREADS (NEDGES / BIN_EPT)            // 75000
#define BIN_BLOCKS ((BIN_THREADS + 255) / 256)    // 293
#define PROJ_NPB 16
#define PROJ_BLOCKS (NNODES / PROJ_NPB)           // 6250 (exact)
#define CUR_PAD 16                                // 64B-padded global cursors
#define QN ((size_t)NNODES * 8)                   // floats per quarter-plane

// ---- cursor init: gcur[b] = b*PCAP ----
__global__ __launch_bounds__(256) void k_initcur(int* __restrict__ gcur) {
    int i = blockIdx.x * 256 + threadIdx.x;
    if (i < NBUCK) gcur[i * CUR_PAD] = i * PCAP;
}

// ---- fused: blocks [0,BIN_BLOCKS) bin edges; rest project h0 = X@W^T ----
// h0 layout: [4][NNODES][8] quarter-planes (3.2 MB each, fits an XCD L2).
__global__ __launch_bounds__(256) void k_binproj(const int4* __restrict__ src4,
                                                 const int4* __restrict__ dst4,
                                                 int* __restrict__ gcur,
                                                 unsigned* __restrict__ packed,
                                                 const float4* __restrict__ feat4,
                                                 const float4* __restrict__ W4,
                                                 float* __restrict__ h0) {
    __shared__ __align__(16) char smem[12480];
    int tid = threadIdx.x;
    if (blockIdx.x < BIN_BLOCKS) {
        int* cnt = (int*)smem;
        int* base = cnt + NBUCK;
        for (int i = tid; i < NBUCK; i += 256) cnt[i] = 0;
        __syncthreads();
        int gid = blockIdx.x * 256 + tid;
        bool act = gid < BIN_THREADS;
        int4 s4[4], d4[4];
        if (act) {
#pragma unroll
            for (int k = 0; k < 4; ++k) {
                s4[k] = src4[(size_t)gid * 4 + k];
                d4[k] = dst4[(size_t)gid * 4 + k];
                atomicAdd(&cnt[d4[k].x >> 8], 1);
                atomicAdd(&cnt[d4[k].y >> 8], 1);
                atomicAdd(&cnt[d4[k].z >> 8], 1);
                atomicAdd(&cnt[d4[k].w >> 8], 1);
            }
        }
        __syncthreads();
        for (int i = tid; i < NBUCK; i += 256) {
            int c = cnt[i];
            base[i] = c ? atomicAdd(&gcur[i * CUR_PAD], c) : 0;
            cnt[i] = 0;
        }
        __syncthreads();
        if (act) {
#pragma unroll
            for (int k = 0; k < 4; ++k) {
                int ss[4] = {s4[k].x, s4[k].y, s4[k].z, s4[k].w};
                int dd[4] = {d4[k].x, d4[k].y, d4[k].z, d4[k].w};
#pragma unroll
                for (int j = 0; j < 4; ++j) {
                    int b = dd[j] >> 8;
                    int rel = atomicAdd(&cnt[b], 1);
                    packed[base[b] + rel] =
                        ((unsigned)(dd[j] & 255) << 17) | (unsigned)ss[j];
                }
            }
        }
    } else {
        float (*Ws)[INF + 1] = (float (*)[INF + 1])smem;                 // [32][65]
        float (*Fs)[INF + 1] = (float (*)[INF + 1])(smem + 8320);       // [16][65]
        int node0 = (blockIdx.x - BIN_BLOCKS) * PROJ_NPB;
        for (int i = tid; i < 512; i += 256) {
            float4 w = W4[i];
            int f = i * 4, of = f >> 6, k = f & 63;
            Ws[of][k] = w.x; Ws[of][k + 1] = w.y;
            Ws[of][k + 2] = w.z; Ws[of][k + 3] = w.w;
        }
        {
            int n = node0 + (tid >> 4), q = tid & 15;
            float4 v = feat4[(size_t)n * 16 + q];
            int c = q * 4;
            Fs[tid >> 4][c] = v.x; Fs[tid >> 4][c + 1] = v.y;
            Fs[tid >> 4][c + 2] = v.z; Fs[tid >> 4][c + 3] = v.w;
        }
        __syncthreads();
        int ln = tid >> 4, n = node0 + ln;
        int of0 = (tid & 15) * 2;
        float a0 = 0.0f, a1 = 0.0f;
#pragma unroll
        for (int k = 0; k < INF; ++k) {
            float f = Fs[ln][k];
            a0 += f * Ws[of0][k];
            a1 += f * Ws[of0 + 1][k];
        }
        // quarter-plane write: feature of0 -> plane of0>>3, offset of0&7
        float* p = h0 + (size_t)(of0 >> 3) * QN + (size_t)n * 8 + (of0 & 7);
        *(float2*)p = make_float2(a0, a1);
    }
}

// ---- per bucket: degree (LDS), norm, rowse, LDS scatter, coalesced col ----
__global__ __launch_bounds__(256) void k_place(const unsigned* __restrict__ packed,
                                               const int* __restrict__ gcur,
                                               int* __restrict__ col,
                                               int2* __restrict__ rowse,
                                               float* __restrict__ norm) {
    __shared__ unsigned sin_[PCAP];
    __shared__ int stage[PCAP];
    __shared__ int deg[SCAN_B];
    __shared__ int rs[SCAN_B];
    int b = blockIdx.x, tid = threadIdx.x;
    int node0 = b * SCAN_B;
    int nn = (NNODES - node0 < SCAN_B) ? (NNODES - node0) : SCAN_B;
    int ebase = b * PCAP;
    int nedge = gcur[b * CUR_PAD] - ebase;
    deg[tid] = 0;
    __syncthreads();
    for (int i = tid; i < nedge; i += 256) {
        unsigned pk = packed[ebase + i];
        sin_[i] = pk;
        atomicAdd(&deg[pk >> 17], 1);
    }
    __syncthreads();
    int d = deg[tid];
    rs[tid] = d;
    __syncthreads();
    for (int st = 1; st < SCAN_B; st <<= 1) {
        int add = (tid >= st) ? rs[tid - st] : 0;
        __syncthreads();
        rs[tid] += add;
        __syncthreads();
    }
    int myoff = rs[tid] - d;  // exclusive scan within bucket
    if (tid < nn) {
        norm[node0 + tid] = rsqrtf(d < 1 ? 1.0f : (float)d);
        rowse[node0 + tid] = make_int2(ebase + myoff, ebase + myoff + d);
    }
    deg[tid] = myoff;  // reuse as cursor
    __syncthreads();
    for (int i = tid; i < nedge; i += 256) {
        unsigned pk = sin_[i];
        int rel = atomicAdd(&deg[pk >> 17], 1);
        stage[rel] = (int)(pk & 0x1FFFFu);
    }
    __syncthreads();
    for (int i = tid; i < nedge; i += 256) col[ebase + i] = stage[i];
}

// ---- one hop over ONE quarter-plane (8 floats/node) ----
// quarter = (blockIdx&7)>>1: under round-robin block->XCD dispatch each XCD
// touches one 3.2 MB slice -> L2-resident (perf heuristic only).
// uout[q][d] = w(d) * sum_e (FIRST? norm[s]:1) * uin[q][col[e]]; LAST adds bias
// and writes standard [node][32] layout.
template <bool FIRST, bool LAST>
__global__ __launch_bounds__(256) void k_gather(const float* __restrict__ uin,
                                                float* __restrict__ uout,
                                                const int2* __restrict__ rowse,
                                                const int* __restrict__ col,
                                                const float* __restrict__ norm,
                                                const float* __restrict__ bias) {
    int bid = blockIdx.x;
    int q = (bid & 7) >> 1;                  // quarter-plane, XCD-pinned
    int idx = ((bid >> 3) << 1) + (bid & 1); // block seq within quarter
    int node = idx * 32 + (threadIdx.x >> 3);
    if (node >= NNODES) return;
    int lane = threadIdx.x & 7;
    const float* up = uin + (size_t)q * QN + lane;
    int2 se = rowse[node];
    int e = se.x, re = se.y;
    float acc = 0.0f;
    for (; e + 7 < re; e += 8) {
        int s0 = col[e],     s1 = col[e + 1], s2 = col[e + 2], s3 = col[e + 3];
        int s4 = col[e + 4], s5 = col[e + 5], s6 = col[e + 6], s7 = col[e + 7];
        float a0 = up[(size_t)s0 * 8];
        float a1 = up[(size_t)s1 * 8];
        float a2 = up[(size_t)s2 * 8];
        float a3 = up[(size_t)s3 * 8];
        float a4 = up[(size_t)s4 * 8];
        float a5 = up[(size_t)s5 * 8];
        float a6 = up[(size_t)s6 * 8];
        float a7 = up[(size_t)s7 * 8];
        if (FIRST) {
            float w0 = norm[s0], w1 = norm[s1], w2 = norm[s2], w3 = norm[s3];
            float w4 = norm[s4], w5 = norm[s5], w6 = norm[s6], w7 = norm[s7];
            acc += ((w0 * a0 + w1 * a1) + (w2 * a2 + w3 * a3)) +
                   ((w4 * a4 + w5 * a5) + (w6 * a6 + w7 * a7));
        } else {
            acc += ((a0 + a1) + (a2 + a3)) + ((a4 + a5) + (a6 + a7));
        }
    }
    for (; e < re; ++e) {
        int s = col[e];
        float a = up[(size_t)s * 8];
        acc += FIRST ? norm[s] * a : a;
    }
    float nn = norm[node];
    float w = LAST ? nn : nn * nn;
    acc *= w;
    if (LAST) {
        acc += bias[q * 8 + lane];
        uout[(size_t)node * OUTF + q * 8 + lane] = acc;
    } else {
        uout[(size_t)q * QN + (size_t)node * 8 + lane] = acc;
    }
}

extern "C" void kernel_launch(void* const* d_in, const int* in_sizes, int n_in,
                              void* d_out, int out_size, void* d_ws, size_t ws_size,
                              hipStream_t stream) {
    const float* feat = (const float*)d_in[0];
    const int*   src  = (const int*)d_in[1];
    const int*   dst  = (const int*)d_in[2];
    const float* W    = (const float*)d_in[3];
    const float* b    = (const float*)d_in[4];
    float* out = (float*)d_out;

    char* ws = (char*)d_ws;
    size_t off = 0;
    auto alloc = [&](size_t bytes) {
        void* p = ws + off;
        off = (off + bytes + 255) & ~(size_t)255;
        return p;
    };
    float*    norm   = (float*)alloc((size_t)NNODES * 4);
    int2*     rowse  = (int2*)alloc((size_t)NNODES * 8);
    int*      gcur   = (int*)alloc((size_t)NBUCK * CUR_PAD * 4);
    unsigned* packed = (unsigned*)alloc((size_t)NBUCK * PCAP * 4);
    int*      col    = (int*)alloc((size_t)NBUCK * PCAP * 4);
    float*    h0     = (float*)alloc(4 * QN * 4);
    float*    h1     = (float*)alloc(4 * QN * 4);

    // ---- init cursors, then fused {edge binning || projection} ----
    k_initcur<<<(NBUCK + 255) / 256, 256, 0, stream>>>(gcur);
    k_binproj<<<BIN_BLOCKS + PROJ_BLOCKS, 256, 0, stream>>>(
        (const int4*)src, (const int4*)dst, gcur, packed,
        (const float4*)feat, (const float4*)W, h0);
    k_place<<<NBUCK, 256, 0, stream>>>(packed, gcur, col, rowse, norm);

    // ---- 4 hops, quarter-planes XCD-pinned (hop1 applies norm[src]) ----
    // per quarter: ceil(100000/32)=3125 blocks -> 1563 groups of 8
    const int ggrid = 1563 * 8;
    k_gather<true,  false><<<ggrid, 256, 0, stream>>>(h0, h1, rowse, col, norm, nullptr);
    k_gather<false, false><<<ggrid, 256, 0, stream>>>(h1, h0, rowse, col, norm, nullptr);
    k_gather<false, false><<<ggrid, 256, 0, stream>>>(h0, h1, rowse, col, norm, nullptr);
    k_gather<false, true><<<ggrid, 256, 0, stream>>>(h1, out, rowse, col, norm, b);
}

// Round 11
// 138.785 us; speedup vs baseline: 1.7550x; 1.7550x over previous
//
#include <hip/hip_runtime.h>
#include <hip/hip_fp16.h>
#include <cstdint>

#define NNODES 100000
#define NEDGES 1200000
#define INF 64
#define OUTF 32
#define SCAN_B 256
#define NBUCK ((NNODES + SCAN_B - 1) / SCAN_B)   // 391; bucket b = dst >> 8
#define PCAP 4608                                 // slots/bucket (R3/R4-verified)
#define BIN_EPT 16
#define BIN_THREADS (NEDGES / BIN_EPT)            // 75000
#define BIN_BLOCKS ((BIN_THREADS + 255) / 256)    // 293
#define PROJ_NPB 16
#define PROJ_BLOCKS (NNODES / PROJ_NPB)           // 6250 (exact)
#define CUR_PAD 16                                // 64B-padded global cursors

// ---- cursor init: gcur[b] = b*PCAP ----
__global__ __launch_bounds__(256) void k_initcur(int* __restrict__ gcur) {
    int i = blockIdx.x * 256 + threadIdx.x;
    if (i < NBUCK) gcur[i * CUR_PAD] = i * PCAP;
}

// ---- fused: blocks [0,BIN_BLOCKS) bin edges; rest project h0 = X@W^T ----
// h0 stored fp16 (half2-packed); fp32 compute. hop1 applies norm[src].
__global__ __launch_bounds__(256) void k_binproj(const int4* __restrict__ src4,
                                                 const int4* __restrict__ dst4,
                                                 int* __restrict__ gcur,
                                                 unsigned* __restrict__ packed,
                                                 const float4* __restrict__ feat4,
                                                 const float4* __restrict__ W4,
                                                 __half2* __restrict__ h0_p) {
    __shared__ __align__(16) char smem[12480];
    int tid = threadIdx.x;
    if (blockIdx.x < BIN_BLOCKS) {
        int* cnt = (int*)smem;
        int* base = cnt + NBUCK;
        for (int i = tid; i < NBUCK; i += 256) cnt[i] = 0;
        __syncthreads();
        int gid = blockIdx.x * 256 + tid;
        bool act = gid < BIN_THREADS;
        int4 s4[4], d4[4];
        if (act) {
#pragma unroll
            for (int k = 0; k < 4; ++k) {
                s4[k] = src4[(size_t)gid * 4 + k];
                d4[k] = dst4[(size_t)gid * 4 + k];
                atomicAdd(&cnt[d4[k].x >> 8], 1);
                atomicAdd(&cnt[d4[k].y >> 8], 1);
                atomicAdd(&cnt[d4[k].z >> 8], 1);
                atomicAdd(&cnt[d4[k].w >> 8], 1);
            }
        }
        __syncthreads();
        for (int i = tid; i < NBUCK; i += 256) {
            int c = cnt[i];
            base[i] = c ? atomicAdd(&gcur[i * CUR_PAD], c) : 0;
            cnt[i] = 0;
        }
        __syncthreads();
        if (act) {
#pragma unroll
            for (int k = 0; k < 4; ++k) {
                int ss[4] = {s4[k].x, s4[k].y, s4[k].z, s4[k].w};
                int dd[4] = {d4[k].x, d4[k].y, d4[k].z, d4[k].w};
#pragma unroll
                for (int j = 0; j < 4; ++j) {
                    int b = dd[j] >> 8;
                    int rel = atomicAdd(&cnt[b], 1);
                    packed[base[b] + rel] =
                        ((unsigned)(dd[j] & 255) << 17) | (unsigned)ss[j];
                }
            }
        }
    } else {
        float (*Ws)[INF + 1] = (float (*)[INF + 1])smem;                 // [32][65]
        float (*Fs)[INF + 1] = (float (*)[INF + 1])(smem + 8320);       // [16][65]
        int node0 = (blockIdx.x - BIN_BLOCKS) * PROJ_NPB;
        for (int i = tid; i < 512; i += 256) {
            float4 w = W4[i];
            int f = i * 4, of = f >> 6, k = f & 63;
            Ws[of][k] = w.x; Ws[of][k + 1] = w.y;
            Ws[of][k + 2] = w.z; Ws[of][k + 3] = w.w;
        }
        {
            int n = node0 + (tid >> 4), q = tid & 15;
            float4 v = feat4[(size_t)n * 16 + q];
            int c = q * 4;
            Fs[tid >> 4][c] = v.x; Fs[tid >> 4][c + 1] = v.y;
            Fs[tid >> 4][c + 2] = v.z; Fs[tid >> 4][c + 3] = v.w;
        }
        __syncthreads();
        int ln = tid >> 4, n = node0 + ln;
        int of0 = (tid & 15) * 2;
        float a0 = 0.0f, a1 = 0.0f;
#pragma unroll
        for (int k = 0; k < INF; ++k) {
            float f = Fs[ln][k];
            a0 += f * Ws[of0][k];
            a1 += f * Ws[of0 + 1][k];
        }
        h0_p[(size_t)n * 16 + (tid & 15)] = __floats2half2_rn(a0, a1);
    }
}

// ---- per bucket: degree (LDS), norm, rowse, LDS scatter, coalesced col ----
__global__ __launch_bounds__(256) void k_place(const unsigned* __restrict__ packed,
                                               const int* __restrict__ gcur,
                                               int* __restrict__ col,
                                               int2* __restrict__ rowse,
                                               float* __restrict__ norm) {
    __shared__ unsigned sin_[PCAP];
    __shared__ int stage[PCAP];
    __shared__ int deg[SCAN_B];
    __shared__ int rs[SCAN_B];
    int b = blockIdx.x, tid = threadIdx.x;
    int node0 = b * SCAN_B;
    int nn = (NNODES - node0 < SCAN_B) ? (NNODES - node0) : SCAN_B;
    int ebase = b * PCAP;
    int nedge = gcur[b * CUR_PAD] - ebase;
    deg[tid] = 0;
    __syncthreads();
    for (int i = tid; i < nedge; i += 256) {
        unsigned pk = packed[ebase + i];
        sin_[i] = pk;
        atomicAdd(&deg[pk >> 17], 1);
    }
    __syncthreads();
    int d = deg[tid];
    rs[tid] = d;
    __syncthreads();
    for (int st = 1; st < SCAN_B; st <<= 1) {
        int add = (tid >= st) ? rs[tid - st] : 0;
        __syncthreads();
        rs[tid] += add;
        __syncthreads();
    }
    int myoff = rs[tid] - d;  // exclusive scan within bucket
    if (tid < nn) {
        norm[node0 + tid] = rsqrtf(d < 1 ? 1.0f : (float)d);
        rowse[node0 + tid] = make_int2(ebase + myoff, ebase + myoff + d);
    }
    deg[tid] = myoff;  // reuse as cursor
    __syncthreads();
    for (int i = tid; i < nedge; i += 256) {
        unsigned pk = sin_[i];
        int rel = atomicAdd(&deg[pk >> 17], 1);
        stage[rel] = (int)(pk & 0x1FFFFu);
    }
    __syncthreads();
    for (int i = tid; i < nedge; i += 256) col[ebase + i] = stage[i];
}

// ---- one hop: uout[d] = w(d)*sum_e (FIRST? norm[s]:1)*uin[col[e]] (+bias) ----
// u rows: 32 fp16 = 64B; 8 lanes/node, uint2 (4 halves) per lane. fp32 accum.
// w = norm^2 (mid) or norm (last). LAST writes fp32 out + bias.
template <bool FIRST, bool LAST>
__global__ __launch_bounds__(256) void k_gather(const uint2* __restrict__ uin,
                                                void* __restrict__ uout,
                                                const int2* __restrict__ rowse,
                                                const int* __restrict__ col,
                                                const float* __restrict__ norm,
                                                const float4* __restrict__ bias4) {
    int t = blockIdx.x * 256 + threadIdx.x;
    int node = t >> 3;
    if (node >= NNODES) return;
    int lane = t & 7;
    int2 se = rowse[node];
    int e = se.x, re = se.y;
    float4 acc = make_float4(0.f, 0.f, 0.f, 0.f);
    auto accum = [&](uint2 r, float w) {
        float2 f01 = __half22float2(*(const __half2*)&r.x);
        float2 f23 = __half22float2(*(const __half2*)&r.y);
        acc.x += w * f01.x; acc.y += w * f01.y;
        acc.z += w * f23.x; acc.w += w * f23.y;
    };
    for (; e + 7 < re; e += 8) {
        int s0 = col[e],     s1 = col[e + 1], s2 = col[e + 2], s3 = col[e + 3];
        int s4 = col[e + 4], s5 = col[e + 5], s6 = col[e + 6], s7 = col[e + 7];
        uint2 r0 = uin[(size_t)s0 * 8 + lane];
        uint2 r1 = uin[(size_t)s1 * 8 + lane];
        uint2 r2 = uin[(size_t)s2 * 8 + lane];
        uint2 r3 = uin[(size_t)s3 * 8 + lane];
        uint2 r4 = uin[(size_t)s4 * 8 + lane];
        uint2 r5 = uin[(size_t)s5 * 8 + lane];
        uint2 r6 = uin[(size_t)s6 * 8 + lane];
        uint2 r7 = uin[(size_t)s7 * 8 + lane];
        if (FIRST) {
            accum(r0, norm[s0]); accum(r1, norm[s1]);
            accum(r2, norm[s2]); accum(r3, norm[s3]);
            accum(r4, norm[s4]); accum(r5, norm[s5]);
            accum(r6, norm[s6]); accum(r7, norm[s7]);
        } else {
            accum(r0, 1.f); accum(r1, 1.f); accum(r2, 1.f); accum(r3, 1.f);
            accum(r4, 1.f); accum(r5, 1.f); accum(r6, 1.f); accum(r7, 1.f);
        }
    }
    for (; e < re; ++e) {
        int s = col[e];
        accum(uin[(size_t)s * 8 + lane], FIRST ? norm[s] : 1.f);
    }
    float nn = norm[node];
    float w = LAST ? nn : nn * nn;
    acc.x *= w; acc.y *= w; acc.z *= w; acc.w *= w;
    if (LAST) {
        float4 bb = bias4[lane];
        acc.x += bb.x; acc.y += bb.y; acc.z += bb.z; acc.w += bb.w;
        ((float4*)uout)[(size_t)node * 8 + lane] = acc;
    } else {
        uint2 r;
        *(__half2*)&r.x = __floats2half2_rn(acc.x, acc.y);
        *(__half2*)&r.y = __floats2half2_rn(acc.z, acc.w);
        ((uint2*)uout)[(size_t)node * 8 + lane] = r;
    }
}

extern "C" void kernel_launch(void* const* d_in, const int* in_sizes, int n_in,
                              void* d_out, int out_size, void* d_ws, size_t ws_size,
                              hipStream_t stream) {
    const float* feat = (const float*)d_in[0];
    const int*   src  = (const int*)d_in[1];
    const int*   dst  = (const int*)d_in[2];
    const float* W    = (const float*)d_in[3];
    const float* b    = (const float*)d_in[4];
    float* out = (float*)d_out;

    char* ws = (char*)d_ws;
    size_t off = 0;
    auto alloc = [&](size_t bytes) {
        void* p = ws + off;
        off = (off + bytes + 255) & ~(size_t)255;
        return p;
    };
    float*    norm   = (float*)alloc((size_t)NNODES * 4);
    int2*     rowse  = (int2*)alloc((size_t)NNODES * 8);
    int*      gcur   = (int*)alloc((size_t)NBUCK * CUR_PAD * 4);
    unsigned* packed = (unsigned*)alloc((size_t)NBUCK * PCAP * 4);
    int*      col    = (int*)alloc((size_t)NBUCK * PCAP * 4);
    void*     h0     = alloc((size_t)NNODES * OUTF * 2);   // fp16
    void*     h1     = alloc((size_t)NNODES * OUTF * 2);   // fp16

    // ---- init cursors, then fused {edge binning || projection} ----
    k_initcur<<<(NBUCK + 255) / 256, 256, 0, stream>>>(gcur);
    k_binproj<<<BIN_BLOCKS + PROJ_BLOCKS, 256, 0, stream>>>(
        (const int4*)src, (const int4*)dst, gcur, packed,
        (const float4*)feat, (const float4*)W, (__half2*)h0);
    k_place<<<NBUCK, 256, 0, stream>>>(packed, gcur, col, rowse, norm);

    // ---- 4 hops (hop1 applies norm[src]; u-space fp16 thereafter) ----
    const int ggrid = (NNODES * 8 + 255) / 256;
    k_gather<true,  false><<<ggrid, 256, 0, stream>>>(
        (const uint2*)h0, h1, rowse, col, norm, nullptr);
    k_gather<false, false><<<ggrid, 256, 0, stream>>>(
        (const uint2*)h1, h0, rowse, col, norm, nullptr);
    k_gather<false, false><<<ggrid, 256, 0, stream>>>(
        (const uint2*)h0, h1, rowse, col, norm, nullptr);
    k_gather<false, true><<<ggrid, 256, 0, stream>>>(
        (const uint2*)h1, out, rowse, col, norm, (const float4*)b);
}